// Round 11
// baseline (425.963 us; speedup 1.0000x reference)
//
#include <hip/hip_runtime.h>
#include <hip/hip_bf16.h>

using bf16 = __hip_bfloat16;
typedef __attribute__((ext_vector_type(8))) short short8;
typedef __attribute__((ext_vector_type(4))) short short4v;
typedef __attribute__((ext_vector_type(4))) float f32x4;

constexpr int BB = 8;
constexpr int NN = 2048;
constexpr int CC = 256;
constexpr int NTOK = BB * NN;  // 16384
constexpr float TWO_PI = 6.283185307179586f;
constexpr float LOG2_1E4 = 13.287712379549449f;

__device__ __forceinline__ float gelu_f(float x) {
  return 0.5f * x * (1.0f + erff(x * 0.7071067811865475f));
}
__device__ __forceinline__ float us2f(unsigned short u) {
  return __uint_as_float(((unsigned)u) << 16);
}

template <int T>
__device__ __forceinline__ void stats_rows(const float (*buf)[CC], float* mu, float* rs, float eps) {
  __syncthreads();
  int w = threadIdx.x >> 6, l = threadIdx.x & 63;
  if (w < T) {
    float s = 0.f, s2 = 0.f;
#pragma unroll
    for (int j = 0; j < 4; ++j) { float v = buf[w][l + 64 * j]; s += v; s2 += v * v; }
#pragma unroll
    for (int o = 32; o; o >>= 1) { s += __shfl_down(s, o); s2 += __shfl_down(s2, o); }
    if (l == 0) {
      float m = s * (1.f / 256.f);
      float var = fmaxf(s2 * (1.f / 256.f) - m * m, 0.f);
      mu[w] = m; rs[w] = rsqrtf(var + eps);
    }
  }
  __syncthreads();
}

// ---------------- shared MFMA GEMM core (XOR-swizzled LDS) ------------------
// NB=1: single-buffered (24KB LDS -> ~6 blocks/CU; TLP hides staging; best
//       for shallow K=256/512 loops where dbuf has no runway — round 6/7 A/B).
// NB=2: double-buffered 2-phase (for deep K=2048 loops).
#define GLD16(src, dst)                                                       \
  __builtin_amdgcn_global_load_lds(                                           \
      (const __attribute__((address_space(1))) void*)(src),                   \
      (__attribute__((address_space(3))) void*)(dst), 16, 0, 0)

template <int K, int MI, int NB>
__device__ __forceinline__ void gemm_core(
    const bf16* __restrict__ Ap, int lda, const bf16* __restrict__ Bp,
    bf16 (&As)[NB][MI * 32 * 64], bf16 (&Bs)[NB][64 * 64], f32x4 (&acc)[MI][2]) {
  const int tid = threadIdx.x;
  const int w = tid >> 6, l = tid & 63;
  const int srow = l >> 3;
  const int scol = ((l & 7) ^ srow) * 8;  // swizzled source col
  const int rsw = (l & 7) * 8;            // read-side XOR (row&7 == l&7)
  const int wm = w >> 1, wn = w & 1;

  auto stage_tile = [&](int buf, int kt) {
#pragma unroll
    for (int i = 0; i < MI; ++i) {
      int r = (w * MI + i) * 8 + srow;
      GLD16(Ap + (long)r * lda + kt + scol, &As[buf][(w * MI + i) * 512 + l * 8]);
    }
#pragma unroll
    for (int i = 0; i < 2; ++i) {
      int r = (w * 2 + i) * 8 + srow;
      GLD16(Bp + (long)r * K + kt + scol, &Bs[buf][(w * 2 + i) * 512 + l * 8]);
    }
  };
  auto compute = [&](int buf) {
    short8 bfr[2][2];
#pragma unroll
    for (int ni = 0; ni < 2; ++ni)
#pragma unroll
      for (int ks = 0; ks < 2; ++ks)
        bfr[ni][ks] = *(const short8*)&Bs[buf][(wn * 32 + ni * 16 + (l & 15)) * 64 +
                                               ((ks * 32 + (l >> 4) * 8) ^ rsw)];
#pragma unroll
    for (int mi = 0; mi < MI; ++mi) {
#pragma unroll
      for (int ks = 0; ks < 2; ++ks) {
        short8 afr = *(const short8*)&As[buf][(wm * (MI * 16) + mi * 16 + (l & 15)) * 64 +
                                              ((ks * 32 + (l >> 4) * 8) ^ rsw)];
#pragma unroll
        for (int ni = 0; ni < 2; ++ni)
          acc[mi][ni] = __builtin_amdgcn_mfma_f32_16x16x32_bf16(afr, bfr[ni][ks], acc[mi][ni], 0, 0, 0);
      }
    }
  };

  if constexpr (NB == 2) {
    stage_tile(0, 0);
    asm volatile("s_waitcnt vmcnt(0)" ::: "memory");
    __builtin_amdgcn_s_barrier();
    int cur = 0;
    for (int kt = 0; kt < K; kt += 64) {
      const bool more = (kt + 64 < K);
      if (more) stage_tile(cur ^ 1, kt + 64);
      compute(cur);
      if (more) asm volatile("s_waitcnt vmcnt(0)" ::: "memory");
      __builtin_amdgcn_s_barrier();
      cur ^= 1;
    }
  } else {
    for (int kt = 0; kt < K; kt += 64) {
      stage_tile(0, kt);
      __syncthreads();       // drains vmcnt+lgkmcnt, then barrier
      compute(0);
      __syncthreads();       // all reads done before next-iter overwrite
    }
  }
}

// ---------------- k_gemm with fused epilogues (BM=128, BN=64) ---------------
enum { E_BF16 = 0, E_BIAS_RESB_BOTH, E_BIAS_GELU, E_BIAS_RES_F32,
       E_RANK1_GELU, E_GELU, E_RES_BOTH };

template <int K, int EPI>
__global__ void __launch_bounds__(256) k_gemm(
    const bf16* __restrict__ A, int lda, const bf16* __restrict__ Bt,
    long bstride, long zstride, int nOffZ,
    const float* __restrict__ bias, const float* __restrict__ res,
    const bf16* __restrict__ resB, const float* __restrict__ rank1,
    const float* __restrict__ pvec,
    float* __restrict__ outF, bf16* __restrict__ outB, int ldo) {
  __shared__ bf16 As[1][128 * 64];
  __shared__ bf16 Bs[1][64 * 64];
  const int tid = threadIdx.x;
  const int w = tid >> 6, l = tid & 63;
  const int m0 = blockIdx.y * 128, n0 = blockIdx.x * 64;
  const int bidx = m0 >> 11;
  const bf16* Bp = Bt + (long)bidx * bstride + (long)blockIdx.z * zstride + (long)n0 * K;
  f32x4 acc[4][2] = {};
  gemm_core<K, 4, 1>(A + (long)m0 * lda, lda, Bp, As, Bs, acc);
  const int wm = w >> 1, wn = w & 1;
  const int zoff = blockIdx.z * nOffZ;
#pragma unroll
  for (int mi = 0; mi < 4; ++mi) {
#pragma unroll
    for (int ni = 0; ni < 2; ++ni) {
      const int bcol = n0 + wn * 32 + ni * 16 + (l & 15);
      const int ocol = bcol + zoff;
#pragma unroll
      for (int r = 0; r < 4; ++r) {
        const int row = m0 + wm * 64 + mi * 16 + (l >> 4) * 4 + r;
        float v = acc[mi][ni][r];
        const long oidx = (long)row * ldo + ocol;
        if constexpr (EPI == E_BF16) { outB[oidx] = __float2bfloat16(v); }
        else if constexpr (EPI == E_BIAS_RESB_BOTH) {
          v += bias[bcol] + __bfloat162float(resB[oidx]);
          outF[oidx] = v; outB[oidx] = __float2bfloat16(v);
        } else if constexpr (EPI == E_BIAS_GELU) {
          v = gelu_f(v + bias[bcol]); outB[oidx] = __float2bfloat16(v);
        } else if constexpr (EPI == E_BIAS_RES_F32) {
          v += bias[bcol] + res[oidx]; outF[oidx] = v;
        } else if constexpr (EPI == E_RANK1_GELU) {
          v = gelu_f(v + pvec[row] * rank1[bcol]); outB[oidx] = __float2bfloat16(v);
        } else if constexpr (EPI == E_GELU) {
          v = gelu_f(v); outB[oidx] = __float2bfloat16(v);
        } else {  // E_RES_BOTH
          v += res[oidx]; outF[oidx] = v; outB[oidx] = __float2bfloat16(v);
        }
      }
    }
  }
}

// ---------------- k_gemmT: GEMM with TRANSPOSED per-matrix output ----------
template <int K>
__global__ void __launch_bounds__(256) k_gemmT(
    const bf16* __restrict__ A, int lda, const bf16* __restrict__ Bt,
    bf16* __restrict__ T0, bf16* __restrict__ T1, int thresh, int matsPerB) {
  __shared__ union {
    struct { bf16 A[1][128 * 64]; bf16 B[1][64 * 64]; } ab;
    bf16 stage[64 * 132];  // stride 132: u32-packed writes conflict-free
  } sm;
  const int tid = threadIdx.x;
  const int w = tid >> 6, l = tid & 63;
  const int m0 = blockIdx.y * 128, n0 = blockIdx.x * 64;
  f32x4 acc[4][2] = {};
  gemm_core<K, 4, 1>(A + (long)m0 * lda, lda, Bt + (long)n0 * K, sm.ab.A, sm.ab.B, acc);
  const int wm = w >> 1, wn = w & 1;
  __syncthreads();  // done with ab union before stage reuse
  // stage acc tile transposed into LDS (packed u32 writes)
#pragma unroll
  for (int mi = 0; mi < 4; ++mi)
#pragma unroll
    for (int ni = 0; ni < 2; ++ni) {
      int c = wn * 32 + ni * 16 + (l & 15);
      int row0 = wm * 64 + mi * 16 + (l >> 4) * 4;
#pragma unroll
      for (int q = 0; q < 2; ++q) {
        bf16 b0 = __float2bfloat16(acc[mi][ni][2 * q]);
        bf16 b1 = __float2bfloat16(acc[mi][ni][2 * q + 1]);
        unsigned u = (unsigned)*(unsigned short*)&b0 |
                     ((unsigned)*(unsigned short*)&b1 << 16);
        *(unsigned*)&sm.stage[c * 132 + row0 + 2 * q] = u;
      }
    }
  __syncthreads();
  const int b = m0 >> 11, nbase = m0 & 2047;
  const int part = (n0 >= thresh) ? 1 : 0;
  const int cT0 = n0 - (part ? thresh : 0);
  bf16* dst = (part ? T1 : T0) + ((long)(b * matsPerB + (cT0 >> 8))) * 524288
            + (long)(cT0 & 255) * 2048;
  const int c = tid >> 2, ns = tid & 3;
  bf16* rowp = dst + (long)c * 2048 + nbase + ns * 32;
#pragma unroll
  for (int j = 0; j < 4; ++j) {
    short4v lo = *(const short4v*)&sm.stage[c * 132 + ns * 32 + j * 8];
    short4v hi = *(const short4v*)&sm.stage[c * 132 + ns * 32 + j * 8 + 4];
    short8 v;
    v[0] = lo[0]; v[1] = lo[1]; v[2] = lo[2]; v[3] = lo[3];
    v[4] = hi[0]; v[5] = hi[1]; v[6] = hi[2]; v[7] = hi[3];
    *(short8*)&rowp[j * 8] = v;
  }
}

// ---------------- k_atb2: D[mat] = A[mat] * B[mat]^T (both [256][2048]) -----
// Deep K=2048 loop -> keep 2-phase dbuf. MI=2 (64x64 tiles) so the cross
// case gets 512 blocks (2/CU) instead of 256 (1/CU).
template <int MI>
__global__ void __launch_bounds__(256) k_atb2(
    const bf16* __restrict__ A0, const bf16* __restrict__ B0,
    bf16* __restrict__ D0, float scale) {
  __shared__ bf16 As[2][MI * 32 * 64];
  __shared__ bf16 Bs[2][64 * 64];
  const int tid = threadIdx.x;
  const int w = tid >> 6, l = tid & 63;
  const int mat = blockIdx.z;
  const int m0 = blockIdx.y * (MI * 32), n0 = blockIdx.x * 64;
  const bf16* Ap = A0 + (long)mat * 524288 + (long)m0 * 2048;
  const bf16* Bp = B0 + (long)mat * 524288 + (long)n0 * 2048;
  f32x4 acc[MI][2] = {};
  gemm_core<2048, MI, 2>(Ap, 2048, Bp, As, Bs, acc);
  bf16* D = D0 + (long)mat * 65536;
  const int wm = w >> 1, wn = w & 1;
#pragma unroll
  for (int mi = 0; mi < MI; ++mi)
#pragma unroll
    for (int ni = 0; ni < 2; ++ni) {
      int col = n0 + wn * 32 + ni * 16 + (l & 15);
#pragma unroll
      for (int r = 0; r < 4; ++r) {
        int row = m0 + wm * (MI * 16) + mi * 16 + (l >> 4) * 4 + r;
        D[(long)row * 256 + col] = __float2bfloat16(acc[mi][ni][r] * scale);
      }
    }
}

// ---------------- k_normrot: FUSED stats + norm + rotary on Kt[mat] ---------
__global__ void __launch_bounds__(256) k_normrot(
    bf16* __restrict__ Kt, const bf16* __restrict__ csT, int hshift) {
  __shared__ bf16 tile[256][68];
  __shared__ float ps[4][64], ps2[4][64];
  __shared__ float smu[64], srs[64];
  const int mat = blockIdx.y;
  const int tok0 = blockIdx.x * 64;
  const int b = mat >> hshift;
  const int tid = threadIdx.x;
  bf16* base = Kt + (long)mat * 524288 + tok0;
  const int cr = tid >> 3;          // 0..31
  const int cj = (tid & 7) * 8;     // token offset 0..56
#pragma unroll
  for (int g = 0; g < 8; ++g) {
    int c = g * 32 + cr;
    *(short8*)&tile[c][cj] = *(const short8*)&base[(long)c * 2048 + cj];
  }
  __syncthreads();
  {
    const int tk = tid & 63, q = tid >> 6;
    float s = 0.f, s2 = 0.f;
#pragma unroll 8
    for (int cc = 0; cc < 64; ++cc) {
      float v = us2f(*(const unsigned short*)&tile[q * 64 + cc][tk]);
      s += v; s2 += v * v;
    }
    ps[q][tk] = s; ps2[q][tk] = s2;
  }
  __syncthreads();
  if (tid < 64) {
    float s = ps[0][tid] + ps[1][tid] + ps[2][tid] + ps[3][tid];
    float s2 = ps2[0][tid] + ps2[1][tid] + ps2[2][tid] + ps2[3][tid];
    float m = s * (1.f / 256.f);
    smu[tid] = m;
    srs[tid] = rsqrtf(fmaxf(s2 * (1.f / 256.f) - m * m, 0.f) + 1e-5f);
  }
  __syncthreads();
  const long ctok = (long)b * 2048 + tok0 + cj;
#pragma unroll
  for (int g = 0; g < 4; ++g) {
    int c = g * 32 + cr;
    short8 v0 = *(const short8*)&tile[c][cj];
    short8 v1 = *(const short8*)&tile[c + 128][cj];
    const bf16* cop = csT + (long)(c * 2) * 16384 + ctok;
    short8 co8 = *(const short8*)cop;
    short8 si8 = *(const short8*)(cop + 16384);
    short8 o0, o1;
#pragma unroll
    for (int e = 0; e < 8; ++e) {
      float m = smu[cj + e], r = srs[cj + e];
      float a = (us2f((unsigned short)v0[e]) - m) * r;
      float bb = (us2f((unsigned short)v1[e]) - m) * r;
      float co = us2f((unsigned short)co8[e]);
      float si = us2f((unsigned short)si8[e]);
      bf16 t0 = __float2bfloat16(a * co - bb * si);
      bf16 t1 = __float2bfloat16(bb * co + a * si);
      o0[e] = *(short*)&t0; o1[e] = *(short*)&t1;
    }
    *(short8*)&base[(long)c * 2048 + cj] = o0;
    *(short8*)&base[(long)(c + 128) * 2048 + cj] = o1;
  }
}

// token-major instnorm + rotary (4 tokens/block); in may equal out
__global__ void __launch_bounds__(256) k_rotq(
    const bf16* __restrict__ in, bf16* __restrict__ out, const bf16* __restrict__ cs) {
  __shared__ float xr[4][CC];
  __shared__ float mu[4], rs[4];
  int tid = threadIdx.x;
  long tok0 = (long)blockIdx.x * 4;
#pragma unroll
  for (int t = 0; t < 4; ++t) xr[t][tid] = __bfloat162float(in[(tok0 + t) * 256 + tid]);
  stats_rows<4>(xr, mu, rs, 1e-5f);
  int i = tid & 127;
#pragma unroll
  for (int t = 0; t < 4; ++t) {
    float co = __bfloat162float(cs[(tok0 + t) * 256 + i]);
    float si = __bfloat162float(cs[(tok0 + t) * 256 + 128 + i]);
    float n0 = (xr[t][tid] - mu[t]) * rs[t];
    float n1 = (xr[t][tid ^ 128] - mu[t]) * rs[t];
    float o = (tid < 128) ? (n0 * co - n1 * si) : (n0 * co + n1 * si);
    out[(tok0 + t) * 256 + tid] = __float2bfloat16(o);
  }
}

// ---------------- weight prep: 12 transposes, one kernel --------------------
struct WEnt { const float* s; bf16* d; int K; int N; int blk0; };
struct WTab { WEnt e[12]; };

__global__ void __launch_bounds__(256) k_wprep(WTab t) {
  int bid = blockIdx.x;
  int ei = 0;
#pragma unroll
  for (int i = 1; i < 12; ++i)
    if (bid >= t.e[i].blk0) ei = i;
  WEnt e = t.e[ei];
  int local = (bid - e.blk0) * 256 + threadIdx.x;
  if (local < e.K * e.N) {
    int n = local / e.K, k = local - n * e.K;
    e.d[local] = __float2bfloat16(e.s[(long)k * e.N + n]);
  }
}

// ---------------- k_csT: transposed cos/sin table, coalesced writes ---------
__global__ void __launch_bounds__(256) k_csT(
    const float* __restrict__ pos, bf16* __restrict__ csT) {
  const int c = blockIdx.y;
  const int n = blockIdx.x * 256 + threadIdx.x;
  float inv = exp2f(-((float)c * (1.f / 128.f)) * LOG2_1E4);
  float fh = pos[n] * 2048.f * inv;
  float s, co; sincosf(fh, &s, &co);
  csT[(long)(c * 2) * 16384 + n] = __float2bfloat16(co);
  csT[(long)(c * 2 + 1) * 16384 + n] = __float2bfloat16(s);
}

// ---------------- k_pre: fourier feats, token-major cos/sin, pvec, z->bf16 --
__global__ void __launch_bounds__(256) k_pre(
    const float* __restrict__ pos, const float* __restrict__ Bf,
    const float* __restrict__ z, const float* __restrict__ P1,
    bf16* __restrict__ gf, bf16* __restrict__ cs,
    float* __restrict__ pvec, bf16* __restrict__ zb, float* __restrict__ P1L) {
  int tid = threadIdx.x;
  long tok0 = (long)blockIdx.x * 4;
  if (blockIdx.x == 0) P1L[tid] = P1[65536 + tid];
  float p[4];
#pragma unroll
  for (int t = 0; t < 4; ++t) p[t] = pos[tok0 + t];
  if (tid < 4) pvec[tok0 + tid] = p[tid] * 0.0625f;
  float bfc = Bf[tid];
#pragma unroll
  for (int t = 0; t < 4; ++t) {
    float xp = TWO_PI * (p[t] * 0.0625f) * bfc;
    float s, c; sincosf(xp, &s, &c);
    gf[(tok0 + t) * 512 + tid] = __float2bfloat16(gelu_f(s));
    gf[(tok0 + t) * 512 + 256 + tid] = __float2bfloat16(gelu_f(c));
    zb[(tok0 + t) * 256 + tid] = __float2bfloat16(z[(tok0 + t) * 256 + tid]);
  }
  if (tid < 128) {
    float inv = exp2f(-((float)tid * (1.f / 128.f)) * LOG2_1E4);
#pragma unroll
    for (int t = 0; t < 4; ++t) {
      float fh = p[t] * 2048.f * inv;
      float s, c; sincosf(fh, &s, &c);
      cs[(tok0 + t) * 256 + tid] = __float2bfloat16(c);
      cs[(tok0 + t) * 256 + 128 + tid] = __float2bfloat16(s);
    }
  }
}

__global__ void __launch_bounds__(256) k_ln(
    const float* __restrict__ xin, const float* __restrict__ g,
    const float* __restrict__ b, bf16* __restrict__ hout) {
  __shared__ float xr[4][CC];
  __shared__ float mu[4], rs[4];
  int tid = threadIdx.x;
  long tok0 = (long)blockIdx.x * 4;
#pragma unroll
  for (int t = 0; t < 4; ++t) xr[t][tid] = xin[(tok0 + t) * 256 + tid];
  stats_rows<4>(xr, mu, rs, 1e-5f);
  float gv = g[tid], bv = b[tid];
#pragma unroll
  for (int t = 0; t < 4; ++t)
    hout[(tok0 + t) * 256 + tid] = __float2bfloat16((xr[t][tid] - mu[t]) * rs[t] * gv + bv);
}

__global__ void __launch_bounds__(256) k_final(
    const bf16* __restrict__ g2, const float* __restrict__ D3,
    const float* __restrict__ b3, float* __restrict__ u) {
  int w = threadIdx.x >> 6, l = threadIdx.x & 63;
  long tok = (long)blockIdx.x * 4 + w;
  float s = __bfloat162float(g2[tok * 128 + l]) * D3[l]
          + __bfloat162float(g2[tok * 128 + 64 + l]) * D3[64 + l];
#pragma unroll
  for (int o = 32; o; o >>= 1) s += __shfl_down(s, o);
  if (l == 0) u[tok] = s + b3[0];
}

// ======================= launcher ===========================================
extern "C" void kernel_launch(void* const* d_in, const int* in_sizes, int n_in,
                              void* d_out, int out_size, void* d_ws, size_t ws_size,
                              hipStream_t stream) {
  const float* z    = (const float*)d_in[0];
  const float* pos  = (const float*)d_in[1];
  const float* Bf   = (const float*)d_in[2];
  const float* Wc   = (const float*)d_in[3];
  const float* Wkv  = (const float*)d_in[4];
  const float* Woca = (const float*)d_in[5];
  const float* boca = (const float*)d_in[6];
  const float* Wf1  = (const float*)d_in[7];
  const float* bf1  = (const float*)d_in[8];
  const float* Wf2  = (const float*)d_in[9];
  const float* bf2  = (const float*)d_in[10];
  const float* lng  = (const float*)d_in[11];
  const float* lnb  = (const float*)d_in[12];
  const float* P1   = (const float*)d_in[13];
  const float* P2   = (const float*)d_in[14];
  const float* P3   = (const float*)d_in[15];
  const float* Wqkv = (const float*)d_in[16];
  const float* Woda = (const float*)d_in[17];
  const float* boda = (const float*)d_in[18];
  const float* ln2g = (const float*)d_in[19];
  const float* ln2b = (const float*)d_in[20];
  const float* D1   = (const float*)d_in[21];
  const float* D2   = (const float*)d_in[22];
  const float* D3   = (const float*)d_in[23];
  const float* b3   = (const float*)d_in[24];

  float* u  = (float*)d_out;
  float* zp = (float*)d_out + NTOK;

  const long MB = 1048576L;
  char* ws = (char*)d_ws;
  // ---- static region [0, 24MB) ----
  bf16*  cs   = (bf16*)(ws);                    // 8 MB token-major cos/sin
  bf16*  csT  = (bf16*)(ws + 8 * MB);           // 8 MB [128][2][16384]
  float* pvec = (float*)(ws + 16 * MB);         // 64 KB
  long wo = 16 * MB + 65536;
  bf16* WcT   = (bf16*)(ws + wo);               wo += 262144;
  bf16* WkvT  = (bf16*)(ws + wo);               wo += 1048576;
  bf16* WocaT = (bf16*)(ws + wo);               wo += 524288;
  bf16* Wf1T  = (bf16*)(ws + wo);               wo += 131072;
  bf16* Wf2T  = (bf16*)(ws + wo);               wo += 131072;
  bf16* P1T   = (bf16*)(ws + wo);               wo += 131072;
  bf16* P2T   = (bf16*)(ws + wo);               wo += 131072;
  bf16* P3T   = (bf16*)(ws + wo);               wo += 131072;
  bf16* WqkvT = (bf16*)(ws + wo);               wo += 393216;
  bf16* WodaT = (bf16*)(ws + wo);               wo += 131072;
  bf16* D1T   = (bf16*)(ws + wo);               wo += 131072;
  bf16* D2T   = (bf16*)(ws + wo);               wo += 65536;
  float* P1L  = (float*)(ws + wo);              wo += 1024;
  // ---- dynamic arena at 24 MB (round-7 layout; all overlaps are across
  //      sequential launches — no within-launch read/write overlap) ----
  char* AR = ws + 24 * MB;
  bf16*  xb     = (bf16*)(AR);             // [0,8)   W4  -> R10
  bf16*  zb     = (bf16*)(AR + 8 * MB);    // [8,16)  W2  -> R5
  bf16*  gf     = (bf16*)(AR + 48 * MB);   // [48,64) W2  -> R4 (Vt W5 after)
  bf16*  Kt     = (bf16*)(AR + 16 * MB);   // [16,48) W5/6 -> R7
  bf16*  Vt     = (bf16*)(AR + 48 * MB);   // [48,80) W5  -> R7
  bf16*  dotsT  = (bf16*)(AR + 8 * MB);    // [8,12)  W7  -> R9
  bf16*  qrot   = (bf16*)(AR + 16 * MB);   // [16,24) W8  -> R9
  bf16*  merged = (bf16*)(AR + 24 * MB);   // [24,56) W9  -> R10
  float* x2     = (float*)(AR + 56 * MB);  // [56,72) W10 -> R12 (f32)
  bf16*  x2b    = (bf16*)(AR + 72 * MB);   // [72,80) W10 -> R11
  bf16*  t1     = (bf16*)(AR + 8 * MB);    // [8,16)  W11 -> R12
  float* x3     = (float*)(AR + 16 * MB);  // [16,32) W12 -> R16 (f32)
  bf16*  h      = (bf16*)(AR + 32 * MB);   // [32,40) W13 -> R14
  bf16*  p1o    = (bf16*)(AR + 40 * MB);   // [40,48) W14 -> R15
  bf16*  p2o    = (bf16*)(AR + 48 * MB);   // [48,56) W15 -> R16
  bf16*  zpb    = (bf16*)(AR + 56 * MB);   // [56,64) W16 -> R18
  bf16*  q2b    = (bf16*)(AR + 64 * MB);   // [64,72) W17/19 -> R22
  bf16*  k2t    = (bf16*)(AR + 72 * MB);   // [72,80) W18/20 -> R21
  bf16*  v2t    = (bf16*)(AR + 8 * MB);    // [8,16)  W18 -> R21
  bf16*  dots2T = (bf16*)(AR + 16 * MB);   // [16,17) W21 -> R22
  bf16*  att    = (bf16*)(AR + 24 * MB);   // [24,32) W22 -> R23
  float* zd     = (float*)(AR + 32 * MB);  // [32,48) W23 -> R24 (f32)
  bf16*  h2     = (bf16*)(AR + 8 * MB);    // [8,16)  W24 -> R25
  bf16*  g1     = (bf16*)(AR + 16 * MB);   // [16,24) W25 -> R26
  bf16*  g2     = (bf16*)(AR + 24 * MB);   // [24,28) W26 -> R27

  // ---- weight-prep table ----
  WTab tab;
  int nb = 0;
  auto add = [&](int i, const float* s, bf16* d, int K_, int N_) {
    tab.e[i].s = s; tab.e[i].d = d; tab.e[i].K = K_; tab.e[i].N = N_;
    tab.e[i].blk0 = nb; nb += (K_ * N_) / 256;
  };
  add(0, Wc, WcT, 512, 256);
  add(1, Wkv, WkvT, 256, 2048);
  add(2, Woca, WocaT, 1024, 256);
  add(3, Wf1, Wf1T, 256, 256);
  add(4, Wf2, Wf2T, 256, 256);
  add(5, P1, P1T, 256, 256);
  add(6, P2, P2T, 256, 256);
  add(7, P3, P3T, 256, 256);
  add(8, Wqkv, WqkvT, 256, 768);
  add(9, Woda, WodaT, 256, 256);
  add(10, D1, D1T, 256, 256);
  add(11, D2, D2T, 256, 128);
  k_wprep<<<nb, 256, 0, stream>>>(tab);

  k_pre<<<NTOK / 4, 256, 0, stream>>>(pos, Bf, z, P1, gf, cs, pvec, zb, P1L);
  k_csT<<<dim3(NTOK / 256, 128), 256, 0, stream>>>(pos, csT);
  // x = gelu(fourier) @ WcT
  k_gemm<512, E_BF16><<<dim3(4, 128, 1), 256, 0, stream>>>(
      gf, 512, WcT, 0, 0, 0, nullptr, nullptr, nullptr, nullptr, nullptr, nullptr, xb, 256);
  // Kt/Vt = (z @ Wkv) transposed per (b,h)
  k_gemmT<256><<<dim3(32, 128), 256, 0, stream>>>(zb, 256, WkvT, Kt, Vt, 1024, 4);
  // fused instnorm stats + norm + rotary on Kt (in place)
  k_normrot<<<dim3(32, 32), 256, 0, stream>>>(Kt, csT, 2);
  // dotsT[mat] = Vt[mat] * Kt[mat]^T / n   (MI=2 -> 512 blocks, 2/CU)
  k_atb2<2><<<dim3(4, 4, 32), 256, 0, stream>>>(Vt, Kt, dotsT, 1.f / 2048.f);
  k_rotq<<<NTOK / 4, 256, 0, stream>>>(xb, qrot, cs);
  // merged[:, h*256:] = qrot @ dotsT[b,h]
  k_gemm<256, E_BF16><<<dim3(4, 128, 4), 256, 0, stream>>>(
      qrot, 256, dotsT, 262144L, 65536L, 256, nullptr, nullptr, nullptr, nullptr, nullptr,
      nullptr, merged, 1024);
  // x2 = merged @ WocaT + boca + x
  k_gemm<1024, E_BIAS_RESB_BOTH><<<dim3(4, 128, 1), 256, 0, stream>>>(
      merged, 1024, WocaT, 0, 0, 0, boca, nullptr, xb, nullptr, nullptr, x2, x2b, 256);
  // t1 = gelu(x2 @ Wf1 + bf1)
  k_gemm<256, E_BIAS_GELU><<<dim3(4, 128, 1), 256, 0, stream>>>(
      x2b, 256, Wf1T, 0, 0, 0, bf1, nullptr, nullptr, nullptr, nullptr, nullptr, t1, 256);
  // x3 = t1 @ Wf2 + bf2 + x2
  k_gemm<256, E_BIAS_RES_F32><<<dim3(4, 128, 1), 256, 0, stream>>>(
      t1, 256, Wf2T, 0, 0, 0, bf2, x2, nullptr, nullptr, nullptr, x3, nullptr, 256);
  k_ln<<<NTOK / 4, 256, 0, stream>>>(x3, lng, lnb, h);
  // p1o = gelu(h @ P1T + pvec*P1L)
  k_gemm<256, E_RANK1_GELU><<<dim3(4, 128, 1), 256, 0, stream>>>(
      h, 256, P1T, 0, 0, 0, nullptr, nullptr, nullptr, P1L, pvec, nullptr, p1o, 256);
  k_gemm<256, E_GELU><<<dim3(4, 128, 1), 256, 0, stream>>>(
      p1o, 256, P2T, 0, 0, 0, nullptr, nullptr, nullptr, nullptr, nullptr, nullptr, p2o, 256);
  // zp = p2o @ P3T + x3
  k_gemm<256, E_RES_BOTH><<<dim3(4, 128, 1), 256, 0, stream>>>(
      p2o, 256, P3T, 0, 0, 0, nullptr, x3, nullptr, nullptr, nullptr, zp, zpb, 256);
  // q2 token-major; k2/v2 transposed
  k_gemm<256, E_BF16><<<dim3(4, 128, 1), 256, 0, stream>>>(
      zpb, 256, WqkvT, 0, 0, 0, nullptr, nullptr, nullptr, nullptr, nullptr, nullptr, q2b, 256);
  k_gemmT<256><<<dim3(8, 128), 256, 0, stream>>>(zpb, 256, WqkvT + 65536, k2t, v2t, 256, 1);
  k_rotq<<<NTOK / 4, 256, 0, stream>>>(q2b, q2b, cs);
  k_normrot<<<dim3(32, 8), 256, 0, stream>>>(k2t, csT, 0);
  k_atb2<2><<<dim3(4, 4, 8), 256, 0, stream>>>(v2t, k2t, dots2T, 1.f / 2048.f);
  // att = q2' @ dots2T[b]
  k_gemm<256, E_BF16><<<dim3(4, 128, 1), 256, 0, stream>>>(
      q2b, 256, dots2T, 65536L, 0, 0, nullptr, nullptr, nullptr, nullptr, nullptr,
      nullptr, att, 256);
  // zd = att @ WodaT + boda + zp
  k_gemm<256, E_BIAS_RES_F32><<<dim3(4, 128, 1), 256, 0, stream>>>(
      att, 256, WodaT, 0, 0, 0, boda, zp, nullptr, nullptr, nullptr, zd, nullptr, 256);
  k_ln<<<NTOK / 4, 256, 0, stream>>>(zd, ln2g, ln2b, h2);
  k_gemm<256, E_GELU><<<dim3(4, 128, 1), 256, 0, stream>>>(
      h2, 256, D1T, 0, 0, 0, nullptr, nullptr, nullptr, nullptr, nullptr, nullptr, g1, 256);
  k_gemm<256, E_GELU><<<dim3(2, 128, 1), 256, 0, stream>>>(
      g1, 256, D2T, 0, 0, 0, nullptr, nullptr, nullptr, nullptr, nullptr, nullptr, g2, 128);
  k_final<<<NTOK / 4, 256, 0, stream>>>(g2, D3, b3, u);
}

// Round 12
// 398.414 us; speedup vs baseline: 1.0691x; 1.0691x over previous
//
#include <hip/hip_runtime.h>
#include <hip/hip_bf16.h>

using bf16 = __hip_bfloat16;
typedef __attribute__((ext_vector_type(8))) short short8;
typedef __attribute__((ext_vector_type(4))) short short4v;
typedef __attribute__((ext_vector_type(4))) float f32x4;

constexpr int BB = 8;
constexpr int NN = 2048;
constexpr int CC = 256;
constexpr int NTOK = BB * NN;  // 16384
constexpr float TWO_PI = 6.283185307179586f;
constexpr float LOG2_1E4 = 13.287712379549449f;

__device__ __forceinline__ float gelu_f(float x) {
  return 0.5f * x * (1.0f + erff(x * 0.7071067811865475f));
}
__device__ __forceinline__ float us2f(unsigned short u) {
  return __uint_as_float(((unsigned)u) << 16);
}
// Bijective XCD-chunk swizzle (requires nwg % 8 == 0): XCD k owns a
// contiguous chunk of remapped ids -> L2 locality for shared panels.
__device__ __forceinline__ int xcd_swz(int f, int nwg) {
  return (f & 7) * (nwg >> 3) + (f >> 3);
}

template <int T>
__device__ __forceinline__ void stats_rows(const float (*buf)[CC], float* mu, float* rs, float eps) {
  __syncthreads();
  int w = threadIdx.x >> 6, l = threadIdx.x & 63;
  if (w < T) {
    float s = 0.f, s2 = 0.f;
#pragma unroll
    for (int j = 0; j < 4; ++j) { float v = buf[w][l + 64 * j]; s += v; s2 += v * v; }
#pragma unroll
    for (int o = 32; o; o >>= 1) { s += __shfl_down(s, o); s2 += __shfl_down(s2, o); }
    if (l == 0) {
      float m = s * (1.f / 256.f);
      float var = fmaxf(s2 * (1.f / 256.f) - m * m, 0.f);
      mu[w] = m; rs[w] = rsqrtf(var + eps);
    }
  }
  __syncthreads();
}

// ---------------- shared MFMA GEMM core (XOR-swizzled LDS) ------------------
// NB=1: single-buffered (24KB LDS; TLP hides staging; best for K<=512).
// NB=2: double-buffered 2-phase (deep K=2048 loops).
#define GLD16(src, dst)                                                       \
  __builtin_amdgcn_global_load_lds(                                           \
      (const __attribute__((address_space(1))) void*)(src),                   \
      (__attribute__((address_space(3))) void*)(dst), 16, 0, 0)

template <int K, int MI, int NB>
__device__ __forceinline__ void gemm_core(
    const bf16* __restrict__ Ap, int lda, const bf16* __restrict__ Bp,
    bf16 (&As)[NB][MI * 32 * 64], bf16 (&Bs)[NB][64 * 64], f32x4 (&acc)[MI][2]) {
  const int tid = threadIdx.x;
  const int w = tid >> 6, l = tid & 63;
  const int srow = l >> 3;
  const int scol = ((l & 7) ^ srow) * 8;  // swizzled source col
  const int rsw = (l & 7) * 8;            // read-side XOR (row&7 == l&7)
  const int wm = w >> 1, wn = w & 1;

  auto stage_tile = [&](int buf, int kt) {
#pragma unroll
    for (int i = 0; i < MI; ++i) {
      int r = (w * MI + i) * 8 + srow;
      GLD16(Ap + (long)r * lda + kt + scol, &As[buf][(w * MI + i) * 512 + l * 8]);
    }
#pragma unroll
    for (int i = 0; i < 2; ++i) {
      int r = (w * 2 + i) * 8 + srow;
      GLD16(Bp + (long)r * K + kt + scol, &Bs[buf][(w * 2 + i) * 512 + l * 8]);
    }
  };
  auto compute = [&](int buf) {
    short8 bfr[2][2];
#pragma unroll
    for (int ni = 0; ni < 2; ++ni)
#pragma unroll
      for (int ks = 0; ks < 2; ++ks)
        bfr[ni][ks] = *(const short8*)&Bs[buf][(wn * 32 + ni * 16 + (l & 15)) * 64 +
                                               ((ks * 32 + (l >> 4) * 8) ^ rsw)];
#pragma unroll
    for (int mi = 0; mi < MI; ++mi) {
#pragma unroll
      for (int ks = 0; ks < 2; ++ks) {
        short8 afr = *(const short8*)&As[buf][(wm * (MI * 16) + mi * 16 + (l & 15)) * 64 +
                                              ((ks * 32 + (l >> 4) * 8) ^ rsw)];
#pragma unroll
        for (int ni = 0; ni < 2; ++ni)
          acc[mi][ni] = __builtin_amdgcn_mfma_f32_16x16x32_bf16(afr, bfr[ni][ks], acc[mi][ni], 0, 0, 0);
      }
    }
  };

  if constexpr (NB == 2) {
    stage_tile(0, 0);
    asm volatile("s_waitcnt vmcnt(0)" ::: "memory");
    __builtin_amdgcn_s_barrier();
    int cur = 0;
    for (int kt = 0; kt < K; kt += 64) {
      const bool more = (kt + 64 < K);
      if (more) stage_tile(cur ^ 1, kt + 64);
      compute(cur);
      if (more) asm volatile("s_waitcnt vmcnt(0)" ::: "memory");
      __builtin_amdgcn_s_barrier();
      cur ^= 1;
    }
  } else {
    for (int kt = 0; kt < K; kt += 64) {
      stage_tile(0, kt);
      __syncthreads();
      compute(0);
      __syncthreads();
    }
  }
}

// ---------------- k_gemm with fused epilogues (BM=128, BN=64) ---------------
enum { E_BF16 = 0, E_BIAS_RESB_BOTH, E_BIAS_GELU, E_BIAS_RES_F32,
       E_RANK1_GELU, E_GELU, E_RES_BOTH };

template <int K, int EPI>
__global__ void __launch_bounds__(256) k_gemm(
    const bf16* __restrict__ A, int lda, const bf16* __restrict__ Bt,
    long bstride, long zstride, int nOffZ,
    const float* __restrict__ bias, const float* __restrict__ res,
    const bf16* __restrict__ resB, const float* __restrict__ rank1,
    const float* __restrict__ pvec,
    float* __restrict__ outF, bf16* __restrict__ outB, int ldo) {
  __shared__ bf16 As[1][128 * 64];
  __shared__ bf16 Bs[1][64 * 64];
  const int tid = threadIdx.x;
  const int w = tid >> 6, l = tid & 63;
  const int m0 = blockIdx.y * 128, n0 = blockIdx.x * 64;
  const int bidx = m0 >> 11;
  const bf16* Bp = Bt + (long)bidx * bstride + (long)blockIdx.z * zstride + (long)n0 * K;
  f32x4 acc[4][2] = {};
  gemm_core<K, 4, 1>(A + (long)m0 * lda, lda, Bp, As, Bs, acc);
  const int wm = w >> 1, wn = w & 1;
  const int zoff = blockIdx.z * nOffZ;
#pragma unroll
  for (int mi = 0; mi < 4; ++mi) {
#pragma unroll
    for (int ni = 0; ni < 2; ++ni) {
      const int bcol = n0 + wn * 32 + ni * 16 + (l & 15);
      const int ocol = bcol + zoff;
#pragma unroll
      for (int r = 0; r < 4; ++r) {
        const int row = m0 + wm * 64 + mi * 16 + (l >> 4) * 4 + r;
        float v = acc[mi][ni][r];
        const long oidx = (long)row * ldo + ocol;
        if constexpr (EPI == E_BF16) { outB[oidx] = __float2bfloat16(v); }
        else if constexpr (EPI == E_BIAS_RESB_BOTH) {
          v += bias[bcol] + __bfloat162float(resB[oidx]);
          outF[oidx] = v; outB[oidx] = __float2bfloat16(v);
        } else if constexpr (EPI == E_BIAS_GELU) {
          v = gelu_f(v + bias[bcol]); outB[oidx] = __float2bfloat16(v);
        } else if constexpr (EPI == E_BIAS_RES_F32) {
          v += bias[bcol] + res[oidx]; outF[oidx] = v;
        } else if constexpr (EPI == E_RANK1_GELU) {
          v = gelu_f(v + pvec[row] * rank1[bcol]); outB[oidx] = __float2bfloat16(v);
        } else if constexpr (EPI == E_GELU) {
          v = gelu_f(v); outB[oidx] = __float2bfloat16(v);
        } else {  // E_RES_BOTH
          v += res[oidx]; outF[oidx] = v; outB[oidx] = __float2bfloat16(v);
        }
      }
    }
  }
}

// ---------------- k_gemmT: GEMM with TRANSPOSED per-matrix output ----------
// 1D grid + XCD swizzle (blocks sharing an A-panel stay on one XCD's L2).
// Store pattern: per instruction, each wave writes 16 FULL 64B lines
// (lane quads contiguous in bytes; j-loop steps 64B).
template <int K>
__global__ void __launch_bounds__(256) k_gemmT(
    const bf16* __restrict__ A, int lda, const bf16* __restrict__ Bt, int nx,
    bf16* __restrict__ T0, bf16* __restrict__ T1, int thresh, int matsPerB) {
  __shared__ union {
    struct { bf16 A[1][128 * 64]; bf16 B[1][64 * 64]; } ab;
    bf16 stage[64 * 132];
  } sm;
  const int tid = threadIdx.x;
  const int w = tid >> 6, l = tid & 63;
  const int f = xcd_swz(blockIdx.x, gridDim.x);
  const int n0 = (f % nx) * 64;
  const int m0 = (f / nx) * 128;
  f32x4 acc[4][2] = {};
  gemm_core<K, 4, 1>(A + (long)m0 * lda, lda, Bt + (long)n0 * K, sm.ab.A, sm.ab.B, acc);
  const int wm = w >> 1, wn = w & 1;
  __syncthreads();  // done with ab union before stage reuse
#pragma unroll
  for (int mi = 0; mi < 4; ++mi)
#pragma unroll
    for (int ni = 0; ni < 2; ++ni) {
      int c = wn * 32 + ni * 16 + (l & 15);
      int row0 = wm * 64 + mi * 16 + (l >> 4) * 4;
#pragma unroll
      for (int q = 0; q < 2; ++q) {
        bf16 b0 = __float2bfloat16(acc[mi][ni][2 * q]);
        bf16 b1 = __float2bfloat16(acc[mi][ni][2 * q + 1]);
        unsigned u = (unsigned)*(unsigned short*)&b0 |
                     ((unsigned)*(unsigned short*)&b1 << 16);
        *(unsigned*)&sm.stage[c * 132 + row0 + 2 * q] = u;
      }
    }
  __syncthreads();
  const int b = m0 >> 11, nbase = m0 & 2047;
  const int part = (n0 >= thresh) ? 1 : 0;
  const int cT0 = n0 - (part ? thresh : 0);
  bf16* dst = (part ? T1 : T0) + ((long)(b * matsPerB + (cT0 >> 8))) * 524288
            + (long)(cT0 & 255) * 2048;
  const int c = tid >> 2, ns = tid & 3;
  bf16* rowp = dst + (long)c * 2048 + nbase + ns * 8;   // ns*16B within line group
#pragma unroll
  for (int j = 0; j < 4; ++j) {                          // j*64B
    short4v lo = *(const short4v*)&sm.stage[c * 132 + ns * 8 + j * 32];
    short4v hi = *(const short4v*)&sm.stage[c * 132 + ns * 8 + j * 32 + 4];
    short8 v;
    v[0] = lo[0]; v[1] = lo[1]; v[2] = lo[2]; v[3] = lo[3];
    v[4] = hi[0]; v[5] = hi[1]; v[6] = hi[2]; v[7] = hi[3];
    *(short8*)&rowp[j * 32] = v;
  }
}

// ---------------- k_atb2: D[mat] = A[mat] * B[mat]^T (both [256][2048]) -----
// MI=2 (64x64 tiles), 1D grid + XCD swizzle (16 blocks/mat stay on one XCD).
__global__ void __launch_bounds__(256) k_atb2(
    const bf16* __restrict__ A0, const bf16* __restrict__ B0,
    bf16* __restrict__ D0, float scale) {
  __shared__ bf16 As[2][2 * 32 * 64];
  __shared__ bf16 Bs[2][64 * 64];
  const int tid = threadIdx.x;
  const int w = tid >> 6, l = tid & 63;
  const int f = xcd_swz(blockIdx.x, gridDim.x);
  const int n0 = (f & 3) * 64;
  const int m0 = ((f >> 2) & 3) * 64;
  const int mat = f >> 4;
  const bf16* Ap = A0 + (long)mat * 524288 + (long)m0 * 2048;
  const bf16* Bp = B0 + (long)mat * 524288 + (long)n0 * 2048;
  f32x4 acc[2][2] = {};
  gemm_core<2048, 2, 2>(Ap, 2048, Bp, As, Bs, acc);
  bf16* D = D0 + (long)mat * 65536;
  const int wm = w >> 1, wn = w & 1;
#pragma unroll
  for (int mi = 0; mi < 2; ++mi)
#pragma unroll
    for (int ni = 0; ni < 2; ++ni) {
      int col = n0 + wn * 32 + ni * 16 + (l & 15);
#pragma unroll
      for (int r = 0; r < 4; ++r) {
        int row = m0 + wm * 32 + mi * 16 + (l >> 4) * 4 + r;
        D[(long)row * 256 + col] = __float2bfloat16(acc[mi][ni][r] * scale);
      }
    }
}

// ---------------- k_normrot: FUSED stats + norm + rotary on Kt[mat] ---------
__global__ void __launch_bounds__(256) k_normrot(
    bf16* __restrict__ Kt, const bf16* __restrict__ csT, int hshift) {
  __shared__ bf16 tile[256][68];
  __shared__ float ps[4][64], ps2[4][64];
  __shared__ float smu[64], srs[64];
  const int mat = blockIdx.y;
  const int tok0 = blockIdx.x * 64;
  const int b = mat >> hshift;
  const int tid = threadIdx.x;
  bf16* base = Kt + (long)mat * 524288 + tok0;
  const int cr = tid >> 3;
  const int cj = (tid & 7) * 8;
#pragma unroll
  for (int g = 0; g < 8; ++g) {
    int c = g * 32 + cr;
    *(short8*)&tile[c][cj] = *(const short8*)&base[(long)c * 2048 + cj];
  }
  __syncthreads();
  {
    const int tk = tid & 63, q = tid >> 6;
    float s = 0.f, s2 = 0.f;
#pragma unroll 8
    for (int cc = 0; cc < 64; ++cc) {
      float v = us2f(*(const unsigned short*)&tile[q * 64 + cc][tk]);
      s += v; s2 += v * v;
    }
    ps[q][tk] = s; ps2[q][tk] = s2;
  }
  __syncthreads();
  if (tid < 64) {
    float s = ps[0][tid] + ps[1][tid] + ps[2][tid] + ps[3][tid];
    float s2 = ps2[0][tid] + ps2[1][tid] + ps2[2][tid] + ps2[3][tid];
    float m = s * (1.f / 256.f);
    smu[tid] = m;
    srs[tid] = rsqrtf(fmaxf(s2 * (1.f / 256.f) - m * m, 0.f) + 1e-5f);
  }
  __syncthreads();
  const long ctok = (long)b * 2048 + tok0 + cj;
#pragma unroll
  for (int g = 0; g < 4; ++g) {
    int c = g * 32 + cr;
    short8 v0 = *(const short8*)&tile[c][cj];
    short8 v1 = *(const short8*)&tile[c + 128][cj];
    const bf16* cop = csT + (long)(c * 2) * 16384 + ctok;
    short8 co8 = *(const short8*)cop;
    short8 si8 = *(const short8*)(cop + 16384);
    short8 o0, o1;
#pragma unroll
    for (int e = 0; e < 8; ++e) {
      float m = smu[cj + e], r = srs[cj + e];
      float a = (us2f((unsigned short)v0[e]) - m) * r;
      float bb = (us2f((unsigned short)v1[e]) - m) * r;
      float co = us2f((unsigned short)co8[e]);
      float si = us2f((unsigned short)si8[e]);
      bf16 t0 = __float2bfloat16(a * co - bb * si);
      bf16 t1 = __float2bfloat16(bb * co + a * si);
      o0[e] = *(short*)&t0; o1[e] = *(short*)&t1;
    }
    *(short8*)&base[(long)c * 2048 + cj] = o0;
    *(short8*)&base[(long)(c + 128) * 2048 + cj] = o1;
  }
}

// token-major instnorm + rotary (4 tokens/block); in may equal out
__global__ void __launch_bounds__(256) k_rotq(
    const bf16* __restrict__ in, bf16* __restrict__ out, const bf16* __restrict__ cs) {
  __shared__ float xr[4][CC];
  __shared__ float mu[4], rs[4];
  int tid = threadIdx.x;
  long tok0 = (long)blockIdx.x * 4;
#pragma unroll
  for (int t = 0; t < 4; ++t) xr[t][tid] = __bfloat162float(in[(tok0 + t) * 256 + tid]);
  stats_rows<4>(xr, mu, rs, 1e-5f);
  int i = tid & 127;
#pragma unroll
  for (int t = 0; t < 4; ++t) {
    float co = __bfloat162float(cs[(tok0 + t) * 256 + i]);
    float si = __bfloat162float(cs[(tok0 + t) * 256 + 128 + i]);
    float n0 = (xr[t][tid] - mu[t]) * rs[t];
    float n1 = (xr[t][tid ^ 128] - mu[t]) * rs[t];
    float o = (tid < 128) ? (n0 * co - n1 * si) : (n0 * co + n1 * si);
    out[(tok0 + t) * 256 + tid] = __float2bfloat16(o);
  }
}

// ---------------- weight prep: 12 transposes, one kernel --------------------
struct WEnt { const float* s; bf16* d; int K; int N; int blk0; };
struct WTab { WEnt e[12]; };

__global__ void __launch_bounds__(256) k_wprep(WTab t) {
  int bid = blockIdx.x;
  int ei = 0;
#pragma unroll
  for (int i = 1; i < 12; ++i)
    if (bid >= t.e[i].blk0) ei = i;
  WEnt e = t.e[ei];
  int local = (bid - e.blk0) * 256 + threadIdx.x;
  if (local < e.K * e.N) {
    int n = local / e.K, k = local - n * e.K;
    e.d[local] = __float2bfloat16(e.s[(long)k * e.N + n]);
  }
}

// ---------------- k_csT: transposed cos/sin table, coalesced writes ---------
__global__ void __launch_bounds__(256) k_csT(
    const float* __restrict__ pos, bf16* __restrict__ csT) {
  const int c = blockIdx.y;
  const int n = blockIdx.x * 256 + threadIdx.x;
  float inv = exp2f(-((float)c * (1.f / 128.f)) * LOG2_1E4);
  float fh = pos[n] * 2048.f * inv;
  float s, co; sincosf(fh, &s, &co);
  csT[(long)(c * 2) * 16384 + n] = __float2bfloat16(co);
  csT[(long)(c * 2 + 1) * 16384 + n] = __float2bfloat16(s);
}

// ---------------- k_pre: fourier feats, token-major cos/sin, pvec, z->bf16 --
__global__ void __launch_bounds__(256) k_pre(
    const float* __restrict__ pos, const float* __restrict__ Bf,
    const float* __restrict__ z, const float* __restrict__ P1,
    bf16* __restrict__ gf, bf16* __restrict__ cs,
    float* __restrict__ pvec, bf16* __restrict__ zb, float* __restrict__ P1L) {
  int tid = threadIdx.x;
  long tok0 = (long)blockIdx.x * 4;
  if (blockIdx.x == 0) P1L[tid] = P1[65536 + tid];
  float p[4];
#pragma unroll
  for (int t = 0; t < 4; ++t) p[t] = pos[tok0 + t];
  if (tid < 4) pvec[tok0 + tid] = p[tid] * 0.0625f;
  float bfc = Bf[tid];
#pragma unroll
  for (int t = 0; t < 4; ++t) {
    float xp = TWO_PI * (p[t] * 0.0625f) * bfc;
    float s, c; sincosf(xp, &s, &c);
    gf[(tok0 + t) * 512 + tid] = __float2bfloat16(gelu_f(s));
    gf[(tok0 + t) * 512 + 256 + tid] = __float2bfloat16(gelu_f(c));
    zb[(tok0 + t) * 256 + tid] = __float2bfloat16(z[(tok0 + t) * 256 + tid]);
  }
  if (tid < 128) {
    float inv = exp2f(-((float)tid * (1.f / 128.f)) * LOG2_1E4);
#pragma unroll
    for (int t = 0; t < 4; ++t) {
      float fh = p[t] * 2048.f * inv;
      float s, c; sincosf(fh, &s, &c);
      cs[(tok0 + t) * 256 + tid] = __float2bfloat16(c);
      cs[(tok0 + t) * 256 + 128 + tid] = __float2bfloat16(s);
    }
  }
}

__global__ void __launch_bounds__(256) k_ln(
    const float* __restrict__ xin, const float* __restrict__ g,
    const float* __restrict__ b, bf16* __restrict__ hout) {
  __shared__ float xr[4][CC];
  __shared__ float mu[4], rs[4];
  int tid = threadIdx.x;
  long tok0 = (long)blockIdx.x * 4;
#pragma unroll
  for (int t = 0; t < 4; ++t) xr[t][tid] = xin[(tok0 + t) * 256 + tid];
  stats_rows<4>(xr, mu, rs, 1e-5f);
  float gv = g[tid], bv = b[tid];
#pragma unroll
  for (int t = 0; t < 4; ++t)
    hout[(tok0 + t) * 256 + tid] = __float2bfloat16((xr[t][tid] - mu[t]) * rs[t] * gv + bv);
}

__global__ void __launch_bounds__(256) k_final(
    const bf16* __restrict__ g2, const float* __restrict__ D3,
    const float* __restrict__ b3, float* __restrict__ u) {
  int w = threadIdx.x >> 6, l = threadIdx.x & 63;
  long tok = (long)blockIdx.x * 4 + w;
  float s = __bfloat162float(g2[tok * 128 + l]) * D3[l]
          + __bfloat162float(g2[tok * 128 + 64 + l]) * D3[64 + l];
#pragma unroll
  for (int o = 32; o; o >>= 1) s += __shfl_down(s, o);
  if (l == 0) u[tok] = s + b3[0];
}

// ======================= launcher ===========================================
extern "C" void kernel_launch(void* const* d_in, const int* in_sizes, int n_in,
                              void* d_out, int out_size, void* d_ws, size_t ws_size,
                              hipStream_t stream) {
  const float* z    = (const float*)d_in[0];
  const float* pos  = (const float*)d_in[1];
  const float* Bf   = (const float*)d_in[2];
  const float* Wc   = (const float*)d_in[3];
  const float* Wkv  = (const float*)d_in[4];
  const float* Woca = (const float*)d_in[5];
  const float* boca = (const float*)d_in[6];
  const float* Wf1  = (const float*)d_in[7];
  const float* bf1  = (const float*)d_in[8];
  const float* Wf2  = (const float*)d_in[9];
  const float* bf2  = (const float*)d_in[10];
  const float* lng  = (const float*)d_in[11];
  const float* lnb  = (const float*)d_in[12];
  const float* P1   = (const float*)d_in[13];
  const float* P2   = (const float*)d_in[14];
  const float* P3   = (const float*)d_in[15];
  const float* Wqkv = (const float*)d_in[16];
  const float* Woda = (const float*)d_in[17];
  const float* boda = (const float*)d_in[18];
  const float* ln2g = (const float*)d_in[19];
  const float* ln2b = (const float*)d_in[20];
  const float* D1   = (const float*)d_in[21];
  const float* D2   = (const float*)d_in[22];
  const float* D3   = (const float*)d_in[23];
  const float* b3   = (const float*)d_in[24];

  float* u  = (float*)d_out;
  float* zp = (float*)d_out + NTOK;

  const long MB = 1048576L;
  char* ws = (char*)d_ws;
  // ---- static region [0, 24MB) ----
  bf16*  cs   = (bf16*)(ws);                    // 8 MB token-major cos/sin
  bf16*  csT  = (bf16*)(ws + 8 * MB);           // 8 MB [128][2][16384]
  float* pvec = (float*)(ws + 16 * MB);         // 64 KB
  long wo = 16 * MB + 65536;
  bf16* WcT   = (bf16*)(ws + wo);               wo += 262144;
  bf16* WkvT  = (bf16*)(ws + wo);               wo += 1048576;
  bf16* WocaT = (bf16*)(ws + wo);               wo += 524288;
  bf16* Wf1T  = (bf16*)(ws + wo);               wo += 131072;
  bf16* Wf2T  = (bf16*)(ws + wo);               wo += 131072;
  bf16* P1T   = (bf16*)(ws + wo);               wo += 131072;
  bf16* P2T   = (bf16*)(ws + wo);               wo += 131072;
  bf16* P3T   = (bf16*)(ws + wo);               wo += 131072;
  bf16* WqkvT = (bf16*)(ws + wo);               wo += 393216;
  bf16* WodaT = (bf16*)(ws + wo);               wo += 131072;
  bf16* D1T   = (bf16*)(ws + wo);               wo += 131072;
  bf16* D2T   = (bf16*)(ws + wo);               wo += 65536;
  float* P1L  = (float*)(ws + wo);              wo += 1024;
  // ---- dynamic arena at 24 MB (round-7 layout; all overlaps are across
  //      sequential launches — no within-launch read/write overlap) ----
  char* AR = ws + 24 * MB;
  bf16*  xb     = (bf16*)(AR);             // [0,8)   W4  -> R10
  bf16*  zb     = (bf16*)(AR + 8 * MB);    // [8,16)  W2  -> R5
  bf16*  gf     = (bf16*)(AR + 48 * MB);   // [48,64) W2  -> R4 (Vt W5 after)
  bf16*  Kt     = (bf16*)(AR + 16 * MB);   // [16,48) W5/6 -> R7
  bf16*  Vt     = (bf16*)(AR + 48 * MB);   // [48,80) W5  -> R7
  bf16*  dotsT  = (bf16*)(AR + 8 * MB);    // [8,12)  W7  -> R9
  bf16*  qrot   = (bf16*)(AR + 16 * MB);   // [16,24) W8  -> R9
  bf16*  merged = (bf16*)(AR + 24 * MB);   // [24,56) W9  -> R10
  float* x2     = (float*)(AR + 56 * MB);  // [56,72) W10 -> R12 (f32)
  bf16*  x2b    = (bf16*)(AR + 72 * MB);   // [72,80) W10 -> R11
  bf16*  t1     = (bf16*)(AR + 8 * MB);    // [8,16)  W11 -> R12
  float* x3     = (float*)(AR + 16 * MB);  // [16,32) W12 -> R16 (f32)
  bf16*  h      = (bf16*)(AR + 32 * MB);   // [32,40) W13 -> R14
  bf16*  p1o    = (bf16*)(AR + 40 * MB);   // [40,48) W14 -> R15
  bf16*  p2o    = (bf16*)(AR + 48 * MB);   // [48,56) W15 -> R16
  bf16*  zpb    = (bf16*)(AR + 56 * MB);   // [56,64) W16 -> R18
  bf16*  q2b    = (bf16*)(AR + 64 * MB);   // [64,72) W17/19 -> R22
  bf16*  k2t    = (bf16*)(AR + 72 * MB);   // [72,80) W18/20 -> R21
  bf16*  v2t    = (bf16*)(AR + 8 * MB);    // [8,16)  W18 -> R21
  bf16*  dots2T = (bf16*)(AR + 16 * MB);   // [16,17) W21 -> R22
  bf16*  att    = (bf16*)(AR + 24 * MB);   // [24,32) W22 -> R23
  float* zd     = (float*)(AR + 32 * MB);  // [32,48) W23 -> R24 (f32)
  bf16*  h2     = (bf16*)(AR + 8 * MB);    // [8,16)  W24 -> R25
  bf16*  g1     = (bf16*)(AR + 16 * MB);   // [16,24) W25 -> R26
  bf16*  g2     = (bf16*)(AR + 24 * MB);   // [24,28) W26 -> R27

  // ---- weight-prep table ----
  WTab tab;
  int nb = 0;
  auto add = [&](int i, const float* s, bf16* d, int K_, int N_) {
    tab.e[i].s = s; tab.e[i].d = d; tab.e[i].K = K_; tab.e[i].N = N_;
    tab.e[i].blk0 = nb; nb += (K_ * N_) / 256;
  };
  add(0, Wc, WcT, 512, 256);
  add(1, Wkv, WkvT, 256, 2048);
  add(2, Woca, WocaT, 1024, 256);
  add(3, Wf1, Wf1T, 256, 256);
  add(4, Wf2, Wf2T, 256, 256);
  add(5, P1, P1T, 256, 256);
  add(6, P2, P2T, 256, 256);
  add(7, P3, P3T, 256, 256);
  add(8, Wqkv, WqkvT, 256, 768);
  add(9, Woda, WodaT, 256, 256);
  add(10, D1, D1T, 256, 256);
  add(11, D2, D2T, 256, 128);
  k_wprep<<<nb, 256, 0, stream>>>(tab);

  k_pre<<<NTOK / 4, 256, 0, stream>>>(pos, Bf, z, P1, gf, cs, pvec, zb, P1L);
  k_csT<<<dim3(NTOK / 256, 128), 256, 0, stream>>>(pos, csT);
  // x = gelu(fourier) @ WcT
  k_gemm<512, E_BF16><<<dim3(4, 128, 1), 256, 0, stream>>>(
      gf, 512, WcT, 0, 0, 0, nullptr, nullptr, nullptr, nullptr, nullptr, nullptr, xb, 256);
  // Kt/Vt = (z @ Wkv) transposed per (b,h); 1D grid + XCD swizzle
  k_gemmT<256><<<32 * 128, 256, 0, stream>>>(zb, 256, WkvT, 32, Kt, Vt, 1024, 4);
  // fused instnorm stats + norm + rotary on Kt (in place)
  k_normrot<<<dim3(32, 32), 256, 0, stream>>>(Kt, csT, 2);
  // dotsT[mat] = Vt[mat] * Kt[mat]^T / n
  k_atb2<<<512, 256, 0, stream>>>(Vt, Kt, dotsT, 1.f / 2048.f);
  k_rotq<<<NTOK / 4, 256, 0, stream>>>(xb, qrot, cs);
  // merged[:, h*256:] = qrot @ dotsT[b,h]
  k_gemm<256, E_BF16><<<dim3(4, 128, 4), 256, 0, stream>>>(
      qrot, 256, dotsT, 262144L, 65536L, 256, nullptr, nullptr, nullptr, nullptr, nullptr,
      nullptr, merged, 1024);
  // x2 = merged @ WocaT + boca + x
  k_gemm<1024, E_BIAS_RESB_BOTH><<<dim3(4, 128, 1), 256, 0, stream>>>(
      merged, 1024, WocaT, 0, 0, 0, boca, nullptr, xb, nullptr, nullptr, x2, x2b, 256);
  // t1 = gelu(x2 @ Wf1 + bf1)
  k_gemm<256, E_BIAS_GELU><<<dim3(4, 128, 1), 256, 0, stream>>>(
      x2b, 256, Wf1T, 0, 0, 0, bf1, nullptr, nullptr, nullptr, nullptr, nullptr, t1, 256);
  // x3 = t1 @ Wf2 + bf2 + x2
  k_gemm<256, E_BIAS_RES_F32><<<dim3(4, 128, 1), 256, 0, stream>>>(
      t1, 256, Wf2T, 0, 0, 0, bf2, x2, nullptr, nullptr, nullptr, x3, nullptr, 256);
  k_ln<<<NTOK / 4, 256, 0, stream>>>(x3, lng, lnb, h);
  // p1o = gelu(h @ P1T + pvec*P1L)
  k_gemm<256, E_RANK1_GELU><<<dim3(4, 128, 1), 256, 0, stream>>>(
      h, 256, P1T, 0, 0, 0, nullptr, nullptr, nullptr, P1L, pvec, nullptr, p1o, 256);
  k_gemm<256, E_GELU><<<dim3(4, 128, 1), 256, 0, stream>>>(
      p1o, 256, P2T, 0, 0, 0, nullptr, nullptr, nullptr, nullptr, nullptr, nullptr, p2o, 256);
  // zp = p2o @ P3T + x3
  k_gemm<256, E_RES_BOTH><<<dim3(4, 128, 1), 256, 0, stream>>>(
      p2o, 256, P3T, 0, 0, 0, nullptr, x3, nullptr, nullptr, nullptr, zp, zpb, 256);
  // q2 token-major; k2/v2 transposed
  k_gemm<256, E_BF16><<<dim3(4, 128, 1), 256, 0, stream>>>(
      zpb, 256, WqkvT, 0, 0, 0, nullptr, nullptr, nullptr, nullptr, nullptr, nullptr, q2b, 256);
  k_gemmT<256><<<8 * 128, 256, 0, stream>>>(zpb, 256, WqkvT + 65536, 8, k2t, v2t, 256, 1);
  k_rotq<<<NTOK / 4, 256, 0, stream>>>(q2b, q2b, cs);
  k_normrot<<<dim3(32, 8), 256, 0, stream>>>(k2t, csT, 0);
  k_atb2<<<128, 256, 0, stream>>>(v2t, k2t, dots2T, 1.f / 2048.f);
  // att = q2' @ dots2T[b]
  k_gemm<256, E_BF16><<<dim3(4, 128, 1), 256, 0, stream>>>(
      q2b, 256, dots2T, 65536L, 0, 0, nullptr, nullptr, nullptr, nullptr, nullptr,
      nullptr, att, 256);
  // zd = att @ WodaT + boda + zp
  k_gemm<256, E_BIAS_RES_F32><<<dim3(4, 128, 1), 256, 0, stream>>>(
      att, 256, WodaT, 0, 0, 0, boda, zp, nullptr, nullptr, nullptr, zd, nullptr, 256);
  k_ln<<<NTOK / 4, 256, 0, stream>>>(zd, ln2g, ln2b, h2);
  k_gemm<256, E_GELU><<<dim3(4, 128, 1), 256, 0, stream>>>(
      h2, 256, D1T, 0, 0, 0, nullptr, nullptr, nullptr, nullptr, nullptr, nullptr, g1, 256);
  k_gemm<256, E_GELU><<<dim3(2, 128, 1), 256, 0, stream>>>(
      g1, 256, D2T, 0, 0, 0, nullptr, nullptr, nullptr, nullptr, nullptr, nullptr, g2, 128);
  k_final<<<NTOK / 4, 256, 0, stream>>>(g2, D3, b3, u);
}